// Round 2
// baseline (56.835 us; speedup 1.0000x reference)
//
#include <hip/hip_runtime.h>

// Problem constants (match reference)
#define BATCH      8192
#define D_DIM      512
#define NUM_CLS    90
#define K_CENTERS  8

// Native vector type so __builtin_nontemporal_load applies (HIP float4 is a class).
typedef float v4f __attribute__((ext_vector_type(4)));

// Workspace layout (zeroed by a 2KB hipMemsetAsync node each launch):
//   ws + 0    : 8 double accumulator slots, one per 128-B cache line (slot i at i*16 doubles)
//   ws + 1024 : uint32 block-retirement counter
#define N_SLOTS 8

// Single fused kernel. 1024 blocks x 256 threads; one wave (64 lanes) per 2 samples.
// Lane layout: k = lane & 7 (which center), sub = lane >> 3 (which 64-elem chunk of D).
// Per sample: 64-elem fp32 dot via 16 float4 FMA iterations per lane;
// reduce over sub with shfl_xor(8,16,32); then over k with shfl_xor(1,2,4) on (d, d*d).
// Finish: per-block double partial -> one device-scope f64 atomicAdd into a padded slot,
// then last-retiring block (device-scope counter) folds the 8 slots and writes out[0].
__global__ __launch_bounds__(256) void center_loss_fused(
    const float* __restrict__ x,
    const float* __restrict__ centers,
    const int*   __restrict__ labels,
    double*      __restrict__ slots,     // ws + 0
    unsigned*    __restrict__ cnt,       // ws + 1024
    float*       __restrict__ out)
{
    const int wave = threadIdx.x >> 6;   // 0..3
    const int lane = threadIdx.x & 63;
    const int k    = lane & 7;
    const int sub  = lane >> 3;

    const int g = blockIdx.x * 4 + wave; // global wave id, 0..4095

    __shared__ double s_r[4];

    double r = 0.0;
#pragma unroll
    for (int s = 0; s < 2; ++s) {
        const int b = g + s * 4096;      // covers 0..8191 exactly
        const int label = labels[b];
        // v4f index: sub + 8*i -> float offset sub*4 + 32*i (contiguous 128B per iter across sub)
        const v4f* xr = (const v4f*)(x + (size_t)b * D_DIM) + sub;
        const v4f* cr = (const v4f*)(centers + ((size_t)label * K_CENTERS + k) * D_DIM) + sub;

        float acc = 0.0f;
#pragma unroll
        for (int i = 0; i < 16; ++i) {
            v4f xv = __builtin_nontemporal_load(xr + i * 8);  // x: zero reuse, stream it
            v4f cv = cr[i * 8];                               // centers: cached, reused
            acc = fmaf(xv.x, cv.x, acc);
            acc = fmaf(xv.y, cv.y, acc);
            acc = fmaf(xv.z, cv.z, acc);
            acc = fmaf(xv.w, cv.w, acc);
        }
        // reduce across sub (lane bits 3..5)
        acc += __shfl_xor(acc, 8);
        acc += __shfl_xor(acc, 16);
        acc += __shfl_xor(acc, 32);

        const float dk = 1.0f + acc;     // d[b,k], replicated across sub-groups
        float s1 = dk;
        float s2 = dk * dk;
        // reduce across k (lane bits 0..2)
        s1 += __shfl_xor(s1, 1);  s2 += __shfl_xor(s2, 1);
        s1 += __shfl_xor(s1, 2);  s2 += __shfl_xor(s2, 2);
        s1 += __shfl_xor(s1, 4);  s2 += __shfl_xor(s2, 4);

        r += (double)(s2 / s1);          // sum_k w*d = (sum d^2) / (sum d)
    }

    if (lane == 0) s_r[wave] = r;
    __syncthreads();

    if (threadIdx.x == 0) {
        const double p = s_r[0] + s_r[1] + s_r[2] + s_r[3];
        // device-scope f64 add into a cache-line-padded slot (8-way to spread contention)
        double* slot = slots + (size_t)(blockIdx.x & (N_SLOTS - 1)) * 16;
        __hip_atomic_fetch_add(slot, p, __ATOMIC_RELAXED, __HIP_MEMORY_SCOPE_AGENT);
        __threadfence();  // make the slot add visible at device scope before retiring
        const unsigned old = __hip_atomic_fetch_add(cnt, 1u, __ATOMIC_ACQ_REL,
                                                    __HIP_MEMORY_SCOPE_AGENT);
        if (old == gridDim.x - 1) {
            // last block: all slot adds are ordered before their counter bumps
            double t = 0.0;
#pragma unroll
            for (int i = 0; i < N_SLOTS; ++i) {
                // device-scope atomic load: a plain load could be served stale from
                // this XCD's L2 (poison lines cached by the harness's fill)
                t += __hip_atomic_load(slots + (size_t)i * 16, __ATOMIC_RELAXED,
                                       __HIP_MEMORY_SCOPE_AGENT);
            }
            out[0] = (float)(t / (double)BATCH);
        }
    }
}

extern "C" void kernel_launch(void* const* d_in, const int* in_sizes, int n_in,
                              void* d_out, int out_size, void* d_ws, size_t ws_size,
                              hipStream_t stream) {
    const float* x       = (const float*)d_in[0];
    const float* centers = (const float*)d_in[1];
    const int*   labels  = (const int*)d_in[2];
    float*    out   = (float*)d_out;
    double*   slots = (double*)d_ws;                          // 8 slots, 128 B apart
    unsigned* cnt   = (unsigned*)((char*)d_ws + 1024);

    // zero slots + counter (workspace is re-poisoned by the harness every iteration)
    hipMemsetAsync(d_ws, 0, 2048, stream);

    const int nblocks = BATCH / 8;      // 1024 blocks; 4 waves/block, 2 samples/wave
    center_loss_fused<<<nblocks, 256, 0, stream>>>(x, centers, labels, slots, cnt, out);
}

// Round 3
// 32.393 us; speedup vs baseline: 1.7545x; 1.7545x over previous
//
#include <hip/hip_runtime.h>

// Problem constants (match reference)
#define BATCH      8192
#define D_DIM      512
#define NUM_CLS    90
#define K_CENTERS  8

// Native vector type so __builtin_nontemporal_load applies (HIP float4 is a class).
typedef float v4f __attribute__((ext_vector_type(4)));

// Workspace layout (zeroed by a 2KB hipMemsetAsync node each launch):
//   ws + 0    : 8 double accumulator slots, one per 128-B cache line (slot i at i*16 doubles)
//   ws + 1024 : uint32 block-retirement counter
#define N_SLOTS 8

// Single fused kernel. 1024 blocks x 256 threads; one wave (64 lanes) per 2 samples.
// Lane layout: k = lane & 7 (which center), sub = lane >> 3 (which 64-elem chunk of D).
//
// Finish phase, fence-free (round-2 post-mortem: __threadfence / ACQ_REL lowered to
// per-block buffer_wbl2+inv = full L2 sweeps, 1024 of them = ~85 us of serialization):
//   - slot add: RELAXED device-scope f64 atomic -> executes at the device coherence
//     point; globally performed once its return value lands (returning form).
//   - ordering: feed the returned value into an inline-asm s_waitcnt vmcnt(0), THEN
//     bump the retirement counter (RELAXED). RMW-performed-at-coherence-point +
//     program order gives the needed happens-before with zero cache maintenance.
//   - last block: RELAXED device-scope atomic loads (cache-bypassing) of the slots.
__global__ __launch_bounds__(256) void center_loss_fused(
    const float* __restrict__ x,
    const float* __restrict__ centers,
    const int*   __restrict__ labels,
    double*      __restrict__ slots,     // ws + 0
    unsigned*    __restrict__ cnt,       // ws + 1024
    float*       __restrict__ out)
{
    const int wave = threadIdx.x >> 6;   // 0..3
    const int lane = threadIdx.x & 63;
    const int k    = lane & 7;
    const int sub  = lane >> 3;

    const int g = blockIdx.x * 4 + wave; // global wave id, 0..4095

    __shared__ double s_r[4];

    double r = 0.0;
#pragma unroll
    for (int s = 0; s < 2; ++s) {
        const int b = g + s * 4096;      // covers 0..8191 exactly
        const int label = labels[b];
        // v4f index: sub + 8*i -> float offset sub*4 + 32*i (contiguous 128B per iter across sub)
        const v4f* xr = (const v4f*)(x + (size_t)b * D_DIM) + sub;
        const v4f* cr = (const v4f*)(centers + ((size_t)label * K_CENTERS + k) * D_DIM) + sub;

        float acc = 0.0f;
#pragma unroll
        for (int i = 0; i < 16; ++i) {
            v4f xv = __builtin_nontemporal_load(xr + i * 8);  // x: zero reuse, stream it
            v4f cv = cr[i * 8];                               // centers: cached, reused
            acc = fmaf(xv.x, cv.x, acc);
            acc = fmaf(xv.y, cv.y, acc);
            acc = fmaf(xv.z, cv.z, acc);
            acc = fmaf(xv.w, cv.w, acc);
        }
        // reduce across sub (lane bits 3..5)
        acc += __shfl_xor(acc, 8);
        acc += __shfl_xor(acc, 16);
        acc += __shfl_xor(acc, 32);

        const float dk = 1.0f + acc;     // d[b,k], replicated across sub-groups
        float s1 = dk;
        float s2 = dk * dk;
        // reduce across k (lane bits 0..2)
        s1 += __shfl_xor(s1, 1);  s2 += __shfl_xor(s2, 1);
        s1 += __shfl_xor(s1, 2);  s2 += __shfl_xor(s2, 2);
        s1 += __shfl_xor(s1, 4);  s2 += __shfl_xor(s2, 4);

        r += (double)(s2 / s1);          // sum_k w*d = (sum d^2) / (sum d)
    }

    if (lane == 0) s_r[wave] = r;
    __syncthreads();

    if (threadIdx.x == 0) {
        const double p = s_r[0] + s_r[1] + s_r[2] + s_r[3];
        // RELAXED device-scope f64 add into a padded slot; keep the RETURNING form
        // (old value used below) so vmcnt retirement == RMW performed at coherence pt.
        double* slot = slots + (size_t)(blockIdx.x & (N_SLOTS - 1)) * 16;
        double oldv = __hip_atomic_fetch_add(slot, p, __ATOMIC_RELAXED,
                                             __HIP_MEMORY_SCOPE_AGENT);
        // Drain the slot RMW before bumping the counter. No wbl2/inv emitted.
        asm volatile("s_waitcnt vmcnt(0)" : : "v"(oldv) : "memory");
        const unsigned old = __hip_atomic_fetch_add(cnt, 1u, __ATOMIC_RELAXED,
                                                    __HIP_MEMORY_SCOPE_AGENT);
        if (old == gridDim.x - 1) {
            // Last block: every other block's slot add is performed (ordered before
            // its counter bump, all at the coherence point). Atomic loads bypass
            // the non-coherent L1/L2, so no stale poison lines.
            double t = 0.0;
#pragma unroll
            for (int i = 0; i < N_SLOTS; ++i) {
                t += __hip_atomic_load(slots + (size_t)i * 16, __ATOMIC_RELAXED,
                                       __HIP_MEMORY_SCOPE_AGENT);
            }
            out[0] = (float)(t / (double)BATCH);
        }
    }
}

extern "C" void kernel_launch(void* const* d_in, const int* in_sizes, int n_in,
                              void* d_out, int out_size, void* d_ws, size_t ws_size,
                              hipStream_t stream) {
    const float* x       = (const float*)d_in[0];
    const float* centers = (const float*)d_in[1];
    const int*   labels  = (const int*)d_in[2];
    float*    out   = (float*)d_out;
    double*   slots = (double*)d_ws;                          // 8 slots, 128 B apart
    unsigned* cnt   = (unsigned*)((char*)d_ws + 1024);

    // zero slots + counter (workspace is re-poisoned by the harness every iteration)
    hipMemsetAsync(d_ws, 0, 2048, stream);

    const int nblocks = BATCH / 8;      // 1024 blocks; 4 waves/block, 2 samples/wave
    center_loss_fused<<<nblocks, 256, 0, stream>>>(x, centers, labels, slots, cnt, out);
}